// Round 5
// baseline (650.091 us; speedup 1.0000x reference)
//
#include <hip/hip_runtime.h>
#include <hip/hip_cooperative_groups.h>
#include <math.h>

namespace cg = cooperative_groups;

// TransferNet: BSZ=8, E=40000, D=128, R=512, NUM_STEPS=2, K=3, DEG=64
#define BSZ 8
#define E_ENT 40000
#define D_DIM 128
#define K_TOP 3
#define DEG 64
#define M_TRI (K_TOP * DEG)   // 192
#define D3 (3 * D_DIM)        // 384
#define NCH 40                // chunks per row for dense top-1
#define CHUNK 1000            // NCH * CHUNK == E_ENT

#define NB 1536               // grid blocks (co-resident: 6/CU)
#define NT 128                // threads per block

// phase-A block-role ranges (NT=128 threads each)
#define A_ZERO_END 625        // 625*128 float4 = 80000 = 320000 floats
#define A_TR_END   1009       // +384 blocks: 384*128 = 49152 = 384*128 elems
#define A_CQ_END   1025       // +16 blocks: 2 steps x 8 rows
#define A_SA_END   1345       // +320 blocks: 8 rows x 40 chunks

typedef unsigned long long ull;

__device__ __forceinline__ float sigmoidf_(float x) { return 1.0f / (1.0f + expf(-x)); }

// Key preserves jax.lax.top_k order for v >= 0: value desc, tie -> lower index.
__device__ __forceinline__ ull make_key(float v, int idx) {
    return ((ull)__float_as_uint(v) << 32) |
           (ull)(0xFFFFFFFFu - (unsigned int)idx);
}
__device__ __forceinline__ int key_idx(ull k) {
    return (int)(0xFFFFFFFFu - (unsigned int)(k & 0xFFFFFFFFull));
}
__device__ __forceinline__ float key_val(ull k) {
    return __uint_as_float((unsigned int)(k >> 32));
}

__global__ __launch_bounds__(NT) void fused_kernel(
        const float* __restrict__ start,
        const float* __restrict__ rel_emb,
        const float* __restrict__ step_W,
        const float* __restrict__ step_b,
        const int* __restrict__ query,
        const float* __restrict__ W_ih,
        const float* __restrict__ W_hh,
        const float* __restrict__ b_ih,
        const float* __restrict__ b_hh,
        const float* __restrict__ cls_w,
        const float* __restrict__ cls_b,
        const int* __restrict__ kb_triple,
        const int* __restrict__ kb_range,
        float* __restrict__ WT_ih,
        float* __restrict__ WT_hh,
        float* __restrict__ cq,
        ull* __restrict__ keysA,
        float* __restrict__ feat,
        int* __restrict__ objs,
        float* __restrict__ p0,
        int* __restrict__ obj1,
        float* __restrict__ p1,
        float* __restrict__ out) {
    cg::grid_group grid = cg::this_grid();
    const int blk = blockIdx.x;
    const int tid = threadIdx.x;

    __shared__ ull   s_kred[NT];
    __shared__ float s_x[D_DIM];
    __shared__ float s_h[D_DIM];
    __shared__ float s_red[D_DIM];
    __shared__ int   s_so[M_TRI];
    __shared__ float s_sp[M_TRI];
    __shared__ int   s_pick_i[K_TOP];
    __shared__ float s_pick_v[K_TOP];

    // ---------------- phase A: zero | transpose | cq | top-1 stage A ------
    if (blk < A_ZERO_END) {
        int i = blk * NT + tid;                       // < 80000
        ((float4*)out)[i] = float4{0.f, 0.f, 0.f, 0.f};
    } else if (blk < A_TR_END) {
        int i = (blk - A_ZERO_END) * NT + tid;        // < 49152
        int row = i >> 7, col = i & 127;
        float a = W_ih[i], c = W_hh[i];
        WT_ih[col * D3 + row] = a;
        WT_hh[col * D3 + row] = c;
    } else if (blk < A_CQ_END) {
        int g = blk - A_TR_END;
        int t = g >> 3, b = g & 7;
        s_x[tid] = rel_emb[query[b] * D_DIM + tid];
        __syncthreads();
        float acc = step_b[t * D_DIM + tid];
        const float* W = step_W + t * D_DIM * D_DIM;
        for (int k = 0; k < D_DIM; k++) acc += s_x[k] * W[k * D_DIM + tid];
        cq[(t * BSZ + b) * D_DIM + tid] = tanhf(acc);
    } else if (blk < A_SA_END) {
        int g = blk - A_CQ_END;
        int b = g / NCH, c = g % NCH;
        const float* row = start + (size_t)b * E_ENT;
        int base = c * CHUNK;
        ull best = 0ull;
        for (int i = tid; i < CHUNK; i += NT) {
            ull k = make_key(row[base + i], base + i);
            if (k > best) best = k;
        }
        s_kred[tid] = best;
        __syncthreads();
        for (int s = 64; s > 0; s >>= 1) {
            if (tid < s && s_kred[tid + s] > s_kred[tid]) s_kred[tid] = s_kred[tid + s];
            __syncthreads();
        }
        if (tid == 0) keysA[b * NCH + c] = s_kred[0];
    }

    grid.sync();

    // ---------------- phase B: step0 (blocks 0..511) ----------------------
    if (blk < BSZ * DEG) {
        int b = blk >> 6, j = blk & 63;
        int d = tid;
        if (d < 64) s_kred[d] = (d < NCH) ? keysA[b * NCH + d] : 0ull;
        __syncthreads();
        for (int s = 32; s > 0; s >>= 1) {
            if (d < s && s_kred[d + s] > s_kred[d]) s_kred[d] = s_kred[d + s];
            __syncthreads();
        }
        int ent = key_idx(s_kred[0]);
        float sub_p = key_val(s_kred[0]);
        int lo = kb_range[2 * ent], hi = kb_range[2 * ent + 1];
        int tri = lo + j;
        bool vj = tri < hi;
        int tuse = vj ? tri : 0;
        int obj = kb_triple[3 * tuse + 1];
        int rel = kb_triple[3 * tuse + 2];

        s_x[d] = rel_emb[rel * D_DIM + d];
        __syncthreads();

        float ir = b_ih[d], iz = b_ih[D_DIM + d], inn = b_ih[2 * D_DIM + d];
        for (int kk = 0; kk < D_DIM; kk++) {
            const float* wi = WT_ih + kk * D3;
            float xk = s_x[kk];
            ir += xk * wi[d]; iz += xk * wi[D_DIM + d]; inn += xk * wi[2 * D_DIM + d];
        }
        float r = sigmoidf_(ir + b_hh[d]);
        float z = sigmoidf_(iz + b_hh[D_DIM + d]);
        float n = tanhf(inn + r * b_hh[2 * D_DIM + d]);
        float trans = (1.f - z) * n;  // h == 0 at step 0

        s_red[d] = trans * cq[b * D_DIM + d] * cls_w[d];
        __syncthreads();
        for (int s = 64; s > 0; s >>= 1) {
            if (d < s) s_red[d] += s_red[d + s];
            __syncthreads();
        }
        float prob = sigmoidf_(s_red[0] + cls_b[0]);
        float obj_p = vj ? sub_p * prob : 0.f;

        feat[((size_t)b * DEG + j) * D_DIM + d] = trans * obj_p;
        if (d == 0) { objs[b * DEG + j] = obj; p0[b * DEG + j] = obj_p; }
    }

    grid.sync();

    // ---------------- phase C: step1 (all blocks) -------------------------
    {
        int b = blk / (K_TOP * DEG);
        int rem = blk % (K_TOP * DEG);
        int k = rem / DEG, j = rem % DEG;
        int d = tid;

        if (d < DEG) { s_so[d] = objs[b * DEG + d]; s_sp[d] = p0[b * DEG + d]; }
        __syncthreads();

        // candidate top-3: aggregate duplicates, normalize max(v,1), 3-pass
        ull mykey = 0ull; int myobj = -1;
        if (d < DEG) {
            myobj = s_so[d];
            float v = 0.f;
            for (int i = 0; i < DEG; i++) if (s_so[i] == myobj) v += s_sp[i];
            v = v / fmaxf(v, 1.f);
            mykey = make_key(v, myobj);
        }
        for (int p = 0; p < K_TOP; p++) {
            ull k2 = mykey;
            for (int q = 0; q < p; q++) if (myobj == s_pick_i[q]) k2 = 0ull;
            if (d < 64) s_kred[d] = k2;
            __syncthreads();
            for (int s = 32; s > 0; s >>= 1) {
                if (d < s && s_kred[d + s] > s_kred[d]) s_kred[d] = s_kred[d + s];
                __syncthreads();
            }
            if (d == 0) {
                int idx = key_idx(s_kred[0]);
                float val = key_val(s_kred[0]);
                if (idx < 0 || idx >= E_ENT) { idx = p; val = 0.f; }  // <3 positives
                s_pick_i[p] = idx; s_pick_v[p] = val;
            }
            __syncthreads();
        }
        int ent = s_pick_i[k];
        float sub_p = s_pick_v[k];

        // hist[b, ent]: match-and-sum step-0 records
        float hd = 0.f;
        for (int m = 0; m < DEG; m++)
            if (s_so[m] == ent) hd += feat[((size_t)b * DEG + m) * D_DIM + d];
        s_h[d] = hd;

        int lo = kb_range[2 * ent], hi = kb_range[2 * ent + 1];
        int tri = lo + j;
        bool vj = tri < hi;
        int tuse = vj ? tri : 0;
        int obj = kb_triple[3 * tuse + 1];
        int rel = kb_triple[3 * tuse + 2];
        s_x[d] = rel_emb[rel * D_DIM + d];
        __syncthreads();

        float ir = b_ih[d], iz = b_ih[D_DIM + d], inn = b_ih[2 * D_DIM + d];
        float hr = b_hh[d], hz = b_hh[D_DIM + d], hn = b_hh[2 * D_DIM + d];
        for (int kk = 0; kk < D_DIM; kk++) {
            const float* wi = WT_ih + kk * D3;
            const float* wh = WT_hh + kk * D3;
            float xk = s_x[kk], hk = s_h[kk];
            ir += xk * wi[d]; iz += xk * wi[D_DIM + d]; inn += xk * wi[2 * D_DIM + d];
            hr += hk * wh[d]; hz += hk * wh[D_DIM + d]; hn += hk * wh[2 * D_DIM + d];
        }
        float r = sigmoidf_(ir + hr);
        float z = sigmoidf_(iz + hz);
        float n = tanhf(inn + r * hn);
        float trans = (1.f - z) * n + z * hd;

        s_red[d] = trans * cq[(BSZ + b) * D_DIM + d] * cls_w[d];  // t=1 slice
        __syncthreads();
        for (int s = 64; s > 0; s >>= 1) {
            if (d < s) s_red[d] += s_red[d + s];
            __syncthreads();
        }
        float prob = sigmoidf_(s_red[0] + cls_b[0]);
        if (d == 0) {
            int idx = b * M_TRI + k * DEG + j;
            obj1[idx] = obj;
            p1[idx] = vj ? sub_p * prob : 0.f;
        }
    }

    grid.sync();

    // ---------------- phase D: finalize (blocks 0..7) ---------------------
    if (blk < BSZ) {
        int b = blk;
        for (int m = tid; m < M_TRI; m += NT) {
            s_so[m] = obj1[b * M_TRI + m];
            s_sp[m] = p1[b * M_TRI + m];
        }
        __syncthreads();
        for (int m = tid; m < M_TRI; m += NT) {
            int o = s_so[m];
            float v = 0.f;
            for (int i = 0; i < M_TRI; i++) if (s_so[i] == o) v += s_sp[i];
            out[(size_t)b * E_ENT + o] = v / fmaxf(v, 1.f);
        }
    }
}

extern "C" void kernel_launch(void* const* d_in, const int* in_sizes, int n_in,
                              void* d_out, int out_size, void* d_ws, size_t ws_size,
                              hipStream_t stream) {
    const float* start    = (const float*)d_in[0];
    const float* rel_emb  = (const float*)d_in[1];
    const float* step_W   = (const float*)d_in[2];
    const float* step_b   = (const float*)d_in[3];
    const float* W_ih     = (const float*)d_in[4];
    const float* W_hh     = (const float*)d_in[5];
    const float* b_ih     = (const float*)d_in[6];
    const float* b_hh     = (const float*)d_in[7];
    const float* cls_w    = (const float*)d_in[8];
    const float* cls_b    = (const float*)d_in[9];
    const int*   query    = (const int*)d_in[10];
    const int*   kb_triple = (const int*)d_in[11];
    const int*   kb_range  = (const int*)d_in[12];
    float* out = (float*)d_out;

    char* ws = (char*)d_ws;
    float* WT_ih = (float*)ws;  ws += (size_t)D3 * D_DIM * sizeof(float);
    float* WT_hh = (float*)ws;  ws += (size_t)D3 * D_DIM * sizeof(float);
    float* cq    = (float*)ws;  ws += (size_t)2 * BSZ * D_DIM * sizeof(float);
    float* feat  = (float*)ws;  ws += (size_t)BSZ * DEG * D_DIM * sizeof(float);
    int*   objs  = (int*)ws;    ws += (size_t)BSZ * DEG * sizeof(int);
    float* p0    = (float*)ws;  ws += (size_t)BSZ * DEG * sizeof(float);
    ull*   keysA = (ull*)ws;    ws += (size_t)BSZ * NCH * sizeof(ull);
    int*   obj1  = (int*)ws;    ws += (size_t)BSZ * M_TRI * sizeof(int);
    float* p1    = (float*)ws;  ws += (size_t)BSZ * M_TRI * sizeof(float);

    void* args[] = {
        (void*)&start, (void*)&rel_emb, (void*)&step_W, (void*)&step_b,
        (void*)&query, (void*)&W_ih, (void*)&W_hh,
        (void*)&b_ih, (void*)&b_hh, (void*)&cls_w, (void*)&cls_b,
        (void*)&kb_triple, (void*)&kb_range,
        (void*)&WT_ih, (void*)&WT_hh, (void*)&cq, (void*)&keysA,
        (void*)&feat, (void*)&objs, (void*)&p0, (void*)&obj1, (void*)&p1,
        (void*)&out
    };
    hipLaunchCooperativeKernel((void*)fused_kernel, dim3(NB), dim3(NT),
                               args, 0, stream);
}

// Round 6
// 72.413 us; speedup vs baseline: 8.9775x; 8.9775x over previous
//
#include <hip/hip_runtime.h>
#include <math.h>

// TransferNet: BSZ=8, E=40000, D=128, R=512, NUM_STEPS=2, K=3, DEG=64
#define BSZ 8
#define E_ENT 40000
#define D_DIM 128
#define K_TOP 3
#define DEG 64
#define M_TRI (K_TOP * DEG)   // 192
#define D3 (3 * D_DIM)        // 384
#define NCH 40                // chunks per row for dense top-1
#define CHUNK 1000            // NCH * CHUNK == E_ENT

// prep block-role ranges (256 threads each)
#define PZ 313                // 313*256 float4 >= 80000 (zero d_out)
#define PT_END (PZ + 192)     // transpose: 192*256 = 49152 = 384*128
#define PC_END (PT_END + 16)  // cq: 2 steps x 8 rows
#define PS_END (PC_END + 320) // stage-A: 8 rows x 40 chunks

typedef unsigned long long ull;

__device__ __forceinline__ float sigmoidf_(float x) { return 1.0f / (1.0f + expf(-x)); }

// Key preserves jax.lax.top_k order for v >= 0: value desc, tie -> lower index.
__device__ __forceinline__ ull make_key(float v, int idx) {
    return ((ull)__float_as_uint(v) << 32) |
           (ull)(0xFFFFFFFFu - (unsigned int)idx);
}
__device__ __forceinline__ int key_idx(ull k) {
    return (int)(0xFFFFFFFFu - (unsigned int)(k & 0xFFFFFFFFull));
}
__device__ __forceinline__ float key_val(ull k) {
    return __uint_as_float((unsigned int)(k >> 32));
}

// ---------------------------------------------------------------------------
// prep: zero d_out + tickets | transpose weights | cq GEMV | top-1 stage A
// ---------------------------------------------------------------------------
__global__ __launch_bounds__(256) void prep_kernel(
        const float* __restrict__ start,
        const float* __restrict__ rel_emb,
        const float* __restrict__ step_W,
        const float* __restrict__ step_b,
        const int* __restrict__ query,
        const float* __restrict__ W_ih,
        const float* __restrict__ W_hh,
        float* __restrict__ WT_ih,
        float* __restrict__ WT_hh,
        float* __restrict__ cq,
        ull* __restrict__ keysA,
        int* __restrict__ cnt,
        float* __restrict__ out) {
    int blk = blockIdx.x, tid = threadIdx.x;
    __shared__ float xs[D_DIM];
    __shared__ ull red[256];
    if (blk < PZ) {
        if (blk == 0 && tid < BSZ) cnt[tid] = 0;   // zero step1 tickets each call
        int i = blk * 256 + tid;
        if (i < (BSZ * E_ENT) / 4) ((float4*)out)[i] = float4{0.f, 0.f, 0.f, 0.f};
    } else if (blk < PT_END) {
        int i = (blk - PZ) * 256 + tid;            // < 49152
        int row = i >> 7, col = i & 127;
        WT_ih[col * D3 + row] = W_ih[i];
        WT_hh[col * D3 + row] = W_hh[i];
    } else if (blk < PC_END) {
        int g = blk - PT_END;
        int t = g >> 3, b = g & 7;
        if (tid < D_DIM) xs[tid] = rel_emb[query[b] * D_DIM + tid];
        __syncthreads();
        if (tid < D_DIM) {
            float acc = step_b[t * D_DIM + tid];
            const float* W = step_W + t * D_DIM * D_DIM;
            for (int k = 0; k < D_DIM; k++) acc += xs[k] * W[k * D_DIM + tid];
            cq[(t * BSZ + b) * D_DIM + tid] = tanhf(acc);
        }
    } else {
        int g = blk - PC_END;
        int b = g / NCH, c = g % NCH;
        const float* row = start + (size_t)b * E_ENT;
        int base = c * CHUNK;
        ull best = 0ull;
        for (int i = tid; i < CHUNK; i += 256) {
            ull k = make_key(row[base + i], base + i);
            if (k > best) best = k;
        }
        red[tid] = best;
        __syncthreads();
        for (int s = 128; s > 0; s >>= 1) {
            if (tid < s && red[tid + s] > red[tid]) red[tid] = red[tid + s];
            __syncthreads();
        }
        if (tid == 0) keysA[b * NCH + c] = red[0];
    }
}

// ---------------------------------------------------------------------------
// step0: fused 40-key stage-B top-1 + 2 GRU cells per 256-thread block
// (h == 0).  256 blocks: b = blk>>5, edges j = (blk&31)*2 + (tid>>7).
// ---------------------------------------------------------------------------
__global__ __launch_bounds__(256) void step0_kernel(
        const ull* __restrict__ keysA,
        const float* __restrict__ cq,        // t=0 slice
        const float* __restrict__ rel_emb,
        const int* __restrict__ kb_triple,
        const int* __restrict__ kb_range,
        const float* __restrict__ WT_ih,
        const float* __restrict__ b_ih,
        const float* __restrict__ b_hh,
        const float* __restrict__ cls_w,
        const float* __restrict__ cls_b,
        float* __restrict__ feat,
        int* __restrict__ objs,
        float* __restrict__ p0) {
    int blk = blockIdx.x, tid = threadIdx.x;
    int b = blk >> 5, jj = blk & 31;
    int e = tid >> 7, d = tid & 127, j = jj * 2 + e;

    __shared__ ull kred[64];
    __shared__ float s_x[2][D_DIM];
    __shared__ float s_part[2][2];
    __shared__ float s_prob[2];

    if (tid < 64) kred[tid] = (tid < NCH) ? keysA[b * NCH + tid] : 0ull;
    __syncthreads();
    for (int s = 32; s > 0; s >>= 1) {
        if (tid < s && kred[tid + s] > kred[tid]) kred[tid] = kred[tid + s];
        __syncthreads();
    }
    int ent = key_idx(kred[0]);
    float sub_p = key_val(kred[0]);
    int lo = kb_range[2 * ent], hi = kb_range[2 * ent + 1];
    int tri = lo + j;
    bool vj = tri < hi;
    int tu = vj ? tri : 0;
    int obj = kb_triple[3 * tu + 1];
    int rel = kb_triple[3 * tu + 2];
    s_x[e][d] = rel_emb[rel * D_DIM + d];
    __syncthreads();

    float ir = b_ih[d], iz = b_ih[D_DIM + d], inn = b_ih[2 * D_DIM + d];
    for (int kk = 0; kk < D_DIM; kk++) {
        const float* wi = WT_ih + kk * D3;
        float xk = s_x[e][kk];
        ir += xk * wi[d]; iz += xk * wi[D_DIM + d]; inn += xk * wi[2 * D_DIM + d];
    }
    float r = sigmoidf_(ir + b_hh[d]);
    float z = sigmoidf_(iz + b_hh[D_DIM + d]);
    float n = tanhf(inn + r * b_hh[2 * D_DIM + d]);
    float trans = (1.f - z) * n;  // h == 0 at step 0

    float v = trans * cq[b * D_DIM + d] * cls_w[d];
    for (int off = 32; off > 0; off >>= 1) v += __shfl_xor(v, off, 64);
    if ((tid & 63) == 0) s_part[e][(tid >> 6) & 1] = v;
    __syncthreads();
    if (tid < 2) s_prob[tid] = sigmoidf_(s_part[tid][0] + s_part[tid][1] + cls_b[0]);
    __syncthreads();
    float obj_p = vj ? sub_p * s_prob[e] : 0.f;

    feat[((size_t)b * DEG + j) * D_DIM + d] = trans * obj_p;
    if (d == 0) { objs[b * DEG + j] = obj; p0[b * DEG + j] = obj_p; }
}

// ---------------------------------------------------------------------------
// step1: one block = (b, j), 384 threads = 3 GRU cells (k=0..2) sharing one
// weight stream. Fused: candidate top-3 + hist match-sum + GRU + classifier.
// Last block per b (split-K ticket) aggregates all 192 records and writes
// the normalized dense output.  512 blocks x 384 threads.
// ---------------------------------------------------------------------------
__global__ __launch_bounds__(384) void step1_kernel(
        const int* __restrict__ objs,
        const float* __restrict__ p0,
        const float* __restrict__ feat,
        const float* __restrict__ cq,        // full cq; t=1 slice at [BSZ..)
        const float* __restrict__ rel_emb,
        const int* __restrict__ kb_triple,
        const int* __restrict__ kb_range,
        const float* __restrict__ WT_ih,
        const float* __restrict__ WT_hh,
        const float* __restrict__ b_ih,
        const float* __restrict__ b_hh,
        const float* __restrict__ cls_w,
        const float* __restrict__ cls_b,
        int* __restrict__ obj1,
        float* __restrict__ p1,
        int* __restrict__ cnt,
        float* __restrict__ out) {
    int blk = blockIdx.x, tid = threadIdx.x;
    int b = blk >> 6, j = blk & 63;
    int k = tid >> 7, d = tid & 127;

    __shared__ int s_so[DEG];
    __shared__ float s_sp[DEG];
    __shared__ ull kred[64];
    __shared__ int s_pi[K_TOP];
    __shared__ float s_pv[K_TOP];
    __shared__ float s_x[K_TOP][D_DIM];
    __shared__ float s_h[K_TOP][D_DIM];
    __shared__ float s_part[K_TOP][2];
    __shared__ float s_prob[K_TOP];
    __shared__ int s_last;
    __shared__ int s_fo[M_TRI];
    __shared__ float s_fp[M_TRI];

    if (tid < DEG) { s_so[tid] = objs[b * DEG + tid]; s_sp[tid] = p0[b * DEG + tid]; }
    __syncthreads();

    // candidate top-3: aggregate duplicates (ascending = jax scatter order),
    // normalize by max(v,1), 3-pass exclusion
    ull mykey = 0ull; int myobj = -1;
    if (tid < DEG) {
        myobj = s_so[tid];
        float v = 0.f;
        for (int i = 0; i < DEG; i++) if (s_so[i] == myobj) v += s_sp[i];
        v = v / fmaxf(v, 1.f);
        mykey = make_key(v, myobj);
    }
    for (int p = 0; p < K_TOP; p++) {
        ull k2 = mykey;
        for (int q = 0; q < p; q++) if (myobj == s_pi[q]) k2 = 0ull;
        if (tid < 64) kred[tid] = k2;
        __syncthreads();
        for (int s = 32; s > 0; s >>= 1) {
            if (tid < s && kred[tid + s] > kred[tid]) kred[tid] = kred[tid + s];
            __syncthreads();
        }
        if (tid == 0) {
            int idx = key_idx(kred[0]);
            float val = key_val(kred[0]);
            if (idx < 0 || idx >= E_ENT) { idx = p; val = 0.f; }  // <3 positives
            s_pi[p] = idx; s_pv[p] = val;
        }
        __syncthreads();
    }
    int ent = s_pi[k];
    float sub_p = s_pv[k];

    // hist[b, ent]: match-and-sum step-0 records (group k -> its own h)
    float hd = 0.f;
    for (int m = 0; m < DEG; m++)
        if (s_so[m] == ent) hd += feat[((size_t)b * DEG + m) * D_DIM + d];
    s_h[k][d] = hd;

    int lo = kb_range[2 * ent], hi = kb_range[2 * ent + 1];
    int tri = lo + j;
    bool vj = tri < hi;
    int tu = vj ? tri : 0;
    int obj = kb_triple[3 * tu + 1];
    int rel = kb_triple[3 * tu + 2];
    s_x[k][d] = rel_emb[rel * D_DIM + d];
    __syncthreads();

    float ir = b_ih[d], iz = b_ih[D_DIM + d], inn = b_ih[2 * D_DIM + d];
    float hr = b_hh[d], hz = b_hh[D_DIM + d], hn = b_hh[2 * D_DIM + d];
    for (int kk = 0; kk < D_DIM; kk++) {
        const float* wi = WT_ih + kk * D3;
        const float* wh = WT_hh + kk * D3;
        float xk = s_x[k][kk], hk = s_h[k][kk];
        ir += xk * wi[d]; iz += xk * wi[D_DIM + d]; inn += xk * wi[2 * D_DIM + d];
        hr += hk * wh[d]; hz += hk * wh[D_DIM + d]; hn += hk * wh[2 * D_DIM + d];
    }
    float r = sigmoidf_(ir + hr);
    float z = sigmoidf_(iz + hz);
    float n = tanhf(inn + r * hn);
    float trans = (1.f - z) * n + z * hd;

    float v = trans * cq[(BSZ + b) * D_DIM + d] * cls_w[d];  // t=1 slice
    for (int off = 32; off > 0; off >>= 1) v += __shfl_xor(v, off, 64);
    if ((tid & 63) == 0) s_part[k][(tid >> 6) & 1] = v;
    __syncthreads();
    if (tid < K_TOP) s_prob[tid] = sigmoidf_(s_part[tid][0] + s_part[tid][1] + cls_b[0]);
    __syncthreads();
    if (d == 0) {
        int idx = b * M_TRI + k * DEG + j;
        obj1[idx] = obj;
        p1[idx] = vj ? sub_p * s_prob[k] : 0.f;
    }

    // split-K style ticket: last block per b does the finalize
    __syncthreads();
    if (tid == 0) {
        __threadfence();
        s_last = (atomicAdd(&cnt[b], 1) == DEG - 1);
    }
    __syncthreads();
    if (!s_last) return;
    __threadfence();  // acquire: other blocks' records now visible

    if (tid < M_TRI) { s_fo[tid] = obj1[b * M_TRI + tid]; s_fp[tid] = p1[b * M_TRI + tid]; }
    __syncthreads();
    if (tid < M_TRI) {
        int o = s_fo[tid];
        float vv = 0.f;
        for (int i = 0; i < M_TRI; i++) if (s_fo[i] == o) vv += s_fp[i];
        out[(size_t)b * E_ENT + o] = vv / fmaxf(vv, 1.f);
    }
}

extern "C" void kernel_launch(void* const* d_in, const int* in_sizes, int n_in,
                              void* d_out, int out_size, void* d_ws, size_t ws_size,
                              hipStream_t stream) {
    const float* start    = (const float*)d_in[0];
    const float* rel_emb  = (const float*)d_in[1];
    const float* step_W   = (const float*)d_in[2];
    const float* step_b   = (const float*)d_in[3];
    const float* W_ih     = (const float*)d_in[4];
    const float* W_hh     = (const float*)d_in[5];
    const float* b_ih     = (const float*)d_in[6];
    const float* b_hh     = (const float*)d_in[7];
    const float* cls_w    = (const float*)d_in[8];
    const float* cls_b    = (const float*)d_in[9];
    const int*   query    = (const int*)d_in[10];
    const int*   kb_triple = (const int*)d_in[11];
    const int*   kb_range  = (const int*)d_in[12];
    float* out = (float*)d_out;

    char* ws = (char*)d_ws;
    float* WT_ih = (float*)ws;  ws += (size_t)D3 * D_DIM * sizeof(float);
    float* WT_hh = (float*)ws;  ws += (size_t)D3 * D_DIM * sizeof(float);
    float* cq    = (float*)ws;  ws += (size_t)2 * BSZ * D_DIM * sizeof(float);
    float* feat  = (float*)ws;  ws += (size_t)BSZ * DEG * D_DIM * sizeof(float);
    int*   objs  = (int*)ws;    ws += (size_t)BSZ * DEG * sizeof(int);
    float* p0    = (float*)ws;  ws += (size_t)BSZ * DEG * sizeof(float);
    ull*   keysA = (ull*)ws;    ws += (size_t)BSZ * NCH * sizeof(ull);
    int*   obj1  = (int*)ws;    ws += (size_t)BSZ * M_TRI * sizeof(int);
    float* p1    = (float*)ws;  ws += (size_t)BSZ * M_TRI * sizeof(float);
    int*   cnt   = (int*)ws;    ws += (size_t)BSZ * sizeof(int);

    prep_kernel<<<PS_END, 256, 0, stream>>>(
        start, rel_emb, step_W, step_b, query, W_ih, W_hh,
        WT_ih, WT_hh, cq, keysA, cnt, out);

    step0_kernel<<<BSZ * 32, 256, 0, stream>>>(
        keysA, cq, rel_emb, kb_triple, kb_range,
        WT_ih, b_ih, b_hh, cls_w, cls_b,
        feat, objs, p0);

    step1_kernel<<<BSZ * DEG, 384, 0, stream>>>(
        objs, p0, feat, cq, rel_emb, kb_triple, kb_range,
        WT_ih, WT_hh, b_ih, b_hh, cls_w, cls_b,
        obj1, p1, cnt, out);
}

// Round 7
// 70.490 us; speedup vs baseline: 9.2225x; 1.0273x over previous
//
#include <hip/hip_runtime.h>
#include <math.h>

// TransferNet: BSZ=8, E=40000, D=128, R=512, NUM_STEPS=2, K=3, DEG=64
#define BSZ 8
#define E_ENT 40000
#define D_DIM 128
#define K_TOP 3
#define DEG 64
#define M_TRI (K_TOP * DEG)   // 192
#define D3 (3 * D_DIM)        // 384
#define NCH 40                // chunks per row for dense top-1
#define CHUNK 1000            // NCH * CHUNK == E_ENT

// prep block-role ranges (256 threads each)
#define PZ 313                // 313*256 float4 >= 80000 (zero d_out)
#define PT_END (PZ + 192)     // transpose: 192*256 = 49152 = 384*128
#define PC_END (PT_END + 16)  // cq: 2 steps x 8 rows
#define PS_END (PC_END + 320) // stage-A: 8 rows x 40 chunks

typedef unsigned long long ull;

__device__ __forceinline__ float sigmoidf_(float x) { return 1.0f / (1.0f + expf(-x)); }

// Key preserves jax.lax.top_k order for v >= 0: value desc, tie -> lower index.
__device__ __forceinline__ ull make_key(float v, int idx) {
    return ((ull)__float_as_uint(v) << 32) |
           (ull)(0xFFFFFFFFu - (unsigned int)idx);
}
__device__ __forceinline__ int key_idx(ull k) {
    return (int)(0xFFFFFFFFu - (unsigned int)(k & 0xFFFFFFFFull));
}
__device__ __forceinline__ float key_val(ull k) {
    return __uint_as_float((unsigned int)(k >> 32));
}

// ---------------------------------------------------------------------------
// prep: zero d_out + tickets | transpose weights | cq GEMV | top-1 stage A
// ---------------------------------------------------------------------------
__global__ __launch_bounds__(256) void prep_kernel(
        const float* __restrict__ start,
        const float* __restrict__ rel_emb,
        const float* __restrict__ step_W,
        const float* __restrict__ step_b,
        const int* __restrict__ query,
        const float* __restrict__ W_ih,
        const float* __restrict__ W_hh,
        float* __restrict__ WT_ih,
        float* __restrict__ WT_hh,
        float* __restrict__ cq,
        ull* __restrict__ keysA,
        int* __restrict__ cnt,
        float* __restrict__ out) {
    int blk = blockIdx.x, tid = threadIdx.x;
    __shared__ float xs[D_DIM];
    __shared__ ull red[256];
    if (blk < PZ) {
        if (blk == 0 && tid < BSZ) cnt[tid] = 0;   // zero step1 tickets each call
        int i = blk * 256 + tid;
        if (i < (BSZ * E_ENT) / 4) ((float4*)out)[i] = float4{0.f, 0.f, 0.f, 0.f};
    } else if (blk < PT_END) {
        int i = (blk - PZ) * 256 + tid;            // < 49152
        int row = i >> 7, col = i & 127;
        WT_ih[col * D3 + row] = W_ih[i];
        WT_hh[col * D3 + row] = W_hh[i];
    } else if (blk < PC_END) {
        int g = blk - PT_END;
        int t = g >> 3, b = g & 7;
        if (tid < D_DIM) xs[tid] = rel_emb[query[b] * D_DIM + tid];
        __syncthreads();
        if (tid < D_DIM) {
            float acc = step_b[t * D_DIM + tid];
            const float* W = step_W + t * D_DIM * D_DIM;
            for (int k = 0; k < D_DIM; k++) acc += xs[k] * W[k * D_DIM + tid];
            cq[(t * BSZ + b) * D_DIM + tid] = tanhf(acc);
        }
    } else {
        int g = blk - PC_END;
        int b = g / NCH, c = g % NCH;
        const float* row = start + (size_t)b * E_ENT;
        int base = c * CHUNK;
        ull best = 0ull;
        for (int i = tid; i < CHUNK; i += 256) {
            ull k = make_key(row[base + i], base + i);
            if (k > best) best = k;
        }
        red[tid] = best;
        __syncthreads();
        for (int s = 128; s > 0; s >>= 1) {
            if (tid < s && red[tid + s] > red[tid]) red[tid] = red[tid + s];
            __syncthreads();
        }
        if (tid == 0) keysA[b * NCH + c] = red[0];
    }
}

// ---------------------------------------------------------------------------
// step0: fused 40-key stage-B top-1 + 2 GRU cells per 256-thread block
// (h == 0).  256 blocks: b = blk>>5, edges j = (blk&31)*2 + (tid>>7).
// ---------------------------------------------------------------------------
__global__ __launch_bounds__(256) void step0_kernel(
        const ull* __restrict__ keysA,
        const float* __restrict__ cq,        // t=0 slice
        const float* __restrict__ rel_emb,
        const int* __restrict__ kb_triple,
        const int* __restrict__ kb_range,
        const float* __restrict__ WT_ih,
        const float* __restrict__ b_ih,
        const float* __restrict__ b_hh,
        const float* __restrict__ cls_w,
        const float* __restrict__ cls_b,
        float* __restrict__ feat,
        int* __restrict__ objs,
        float* __restrict__ p0) {
    int blk = blockIdx.x, tid = threadIdx.x;
    int b = blk >> 5, jj = blk & 31;
    int e = tid >> 7, d = tid & 127, j = jj * 2 + e;

    __shared__ ull kred[64];
    __shared__ float s_x[2][D_DIM];
    __shared__ float s_part[2][2];
    __shared__ float s_prob[2];

    if (tid < 64) kred[tid] = (tid < NCH) ? keysA[b * NCH + tid] : 0ull;
    __syncthreads();
    for (int s = 32; s > 0; s >>= 1) {
        if (tid < s && kred[tid + s] > kred[tid]) kred[tid] = kred[tid + s];
        __syncthreads();
    }
    int ent = key_idx(kred[0]);
    float sub_p = key_val(kred[0]);
    int lo = kb_range[2 * ent], hi = kb_range[2 * ent + 1];
    int tri = lo + j;
    bool vj = tri < hi;
    int tu = vj ? tri : 0;
    int obj = kb_triple[3 * tu + 1];
    int rel = kb_triple[3 * tu + 2];
    s_x[e][d] = rel_emb[rel * D_DIM + d];
    __syncthreads();

    float ir = b_ih[d], iz = b_ih[D_DIM + d], inn = b_ih[2 * D_DIM + d];
    for (int kk = 0; kk < D_DIM; kk++) {
        const float* wi = WT_ih + kk * D3;
        float xk = s_x[e][kk];
        ir += xk * wi[d]; iz += xk * wi[D_DIM + d]; inn += xk * wi[2 * D_DIM + d];
    }
    float r = sigmoidf_(ir + b_hh[d]);
    float z = sigmoidf_(iz + b_hh[D_DIM + d]);
    float n = tanhf(inn + r * b_hh[2 * D_DIM + d]);
    float trans = (1.f - z) * n;  // h == 0 at step 0

    float v = trans * cq[b * D_DIM + d] * cls_w[d];
    for (int off = 32; off > 0; off >>= 1) v += __shfl_xor(v, off, 64);
    if ((tid & 63) == 0) s_part[e][(tid >> 6) & 1] = v;
    __syncthreads();
    if (tid < 2) s_prob[tid] = sigmoidf_(s_part[tid][0] + s_part[tid][1] + cls_b[0]);
    __syncthreads();
    float obj_p = vj ? sub_p * s_prob[e] : 0.f;

    feat[((size_t)b * DEG + j) * D_DIM + d] = trans * obj_p;
    if (d == 0) { objs[b * DEG + j] = obj; p0[b * DEG + j] = obj_p; }
}

// ---------------------------------------------------------------------------
// mid: per-b (8 blocks x 384 threads):
//  1) candidate top-3 over step-0 records (aggregate dups, normalize, 3-pass)
//  2) h[b][k][d] = sum_m (so[m]==ent_k) * feat[m][d]  (UNCONDITIONAL loads)
//  3) gh[b][k][:] = h @ W_hh^T + b_hh   (the only 24 hh-GEMVs that exist)
// ---------------------------------------------------------------------------
__global__ __launch_bounds__(384) void mid_kernel(
        const int* __restrict__ objs,
        const float* __restrict__ p0,
        const float* __restrict__ feat,
        const float* __restrict__ WT_hh,
        const float* __restrict__ b_hh,
        int* __restrict__ pick_i,
        float* __restrict__ pick_v,
        float* __restrict__ hvec,
        float* __restrict__ gh) {
    int b = blockIdx.x, tid = threadIdx.x;  // 384 threads

    __shared__ int s_so[DEG];
    __shared__ float s_sp[DEG];
    __shared__ ull kred[64];
    __shared__ int s_pi[K_TOP];
    __shared__ float s_pv[K_TOP];
    __shared__ float s_h[K_TOP][D_DIM];

    if (tid < DEG) { s_so[tid] = objs[b * DEG + tid]; s_sp[tid] = p0[b * DEG + tid]; }
    __syncthreads();

    ull mykey = 0ull; int myobj = -1;
    if (tid < DEG) {
        myobj = s_so[tid];
        float v = 0.f;
        for (int i = 0; i < DEG; i++) if (s_so[i] == myobj) v += s_sp[i];
        v = v / fmaxf(v, 1.f);
        mykey = make_key(v, myobj);
    }
    for (int p = 0; p < K_TOP; p++) {
        ull k2 = mykey;
        for (int q = 0; q < p; q++) if (myobj == s_pi[q]) k2 = 0ull;
        if (tid < 64) kred[tid] = k2;
        __syncthreads();
        for (int s = 32; s > 0; s >>= 1) {
            if (tid < s && kred[tid + s] > kred[tid]) kred[tid] = kred[tid + s];
            __syncthreads();
        }
        if (tid == 0) {
            int idx = key_idx(kred[0]);
            float val = key_val(kred[0]);
            if (idx < 0 || idx >= E_ENT) { idx = p; val = 0.f; }  // <3 positives
            s_pi[p] = idx; s_pv[p] = val;
        }
        __syncthreads();
    }
    if (tid < K_TOP) { pick_i[b * K_TOP + tid] = s_pi[tid]; pick_v[b * K_TOP + tid] = s_pv[tid]; }

    // h[b][k][d]: unconditional loads, arithmetic mask (pipelineable)
    {
        int k = tid >> 7, d = tid & 127;
        int ent = s_pi[k];
        float hd = 0.f;
        const float* fb = feat + (size_t)b * DEG * D_DIM + d;
        for (int m = 0; m < DEG; m++) {
            float f = fb[m * D_DIM];
            hd += (s_so[m] == ent) ? f : 0.f;
        }
        s_h[k][d] = hd;
        hvec[((size_t)b * K_TOP + k) * D_DIM + d] = hd;
    }
    __syncthreads();

    // gh[b][k][col] = b_hh[col] + sum_kk h[k][kk] * WT_hh[kk*384+col]
    {
        int col = tid;  // 0..383
        float a0 = b_hh[col], a1 = a0, a2 = a0;
        for (int kk = 0; kk < D_DIM; kk++) {
            float w = WT_hh[kk * D3 + col];
            a0 += s_h[0][kk] * w;
            a1 += s_h[1][kk] * w;
            a2 += s_h[2][kk] * w;
        }
        gh[((size_t)b * K_TOP + 0) * D3 + col] = a0;
        gh[((size_t)b * K_TOP + 1) * D3 + col] = a1;
        gh[((size_t)b * K_TOP + 2) * D3 + col] = a2;
    }
}

// ---------------------------------------------------------------------------
// step1: one block = (b, j), 384 threads = 3 GRU cells (k=0..2).  Pure
// streaming: ih-dots only (gh precomputed), h read directly.  Last block
// per b (ticket) aggregates all 192 records and writes the dense output.
// 512 blocks x 384 threads.
// ---------------------------------------------------------------------------
__global__ __launch_bounds__(384) void step1_kernel(
        const int* __restrict__ pick_i,
        const float* __restrict__ pick_v,
        const float* __restrict__ hvec,
        const float* __restrict__ gh,
        const float* __restrict__ cq,        // full cq; t=1 slice at [BSZ..)
        const float* __restrict__ rel_emb,
        const int* __restrict__ kb_triple,
        const int* __restrict__ kb_range,
        const float* __restrict__ WT_ih,
        const float* __restrict__ b_ih,
        const float* __restrict__ cls_w,
        const float* __restrict__ cls_b,
        int* __restrict__ obj1,
        float* __restrict__ p1,
        int* __restrict__ cnt,
        float* __restrict__ out) {
    int blk = blockIdx.x, tid = threadIdx.x;
    int b = blk >> 6, j = blk & 63;
    int k = tid >> 7, d = tid & 127;

    __shared__ float s_x[K_TOP][D_DIM];
    __shared__ float s_part[K_TOP][2];
    __shared__ float s_prob[K_TOP];
    __shared__ int s_last;
    __shared__ int s_fo[M_TRI];
    __shared__ float s_fp[M_TRI];

    int ent = pick_i[b * K_TOP + k];
    float sub_p = pick_v[b * K_TOP + k];
    int lo = kb_range[2 * ent], hi = kb_range[2 * ent + 1];
    int tri = lo + j;
    bool vj = tri < hi;
    int tu = vj ? tri : 0;
    int obj = kb_triple[3 * tu + 1];
    int rel = kb_triple[3 * tu + 2];
    s_x[k][d] = rel_emb[rel * D_DIM + d];

    size_t hkbase = ((size_t)b * K_TOP + k) * D_DIM;
    size_t gbase = ((size_t)b * K_TOP + k) * D3;
    float hd = hvec[hkbase + d];
    float ghr = gh[gbase + d];
    float ghz = gh[gbase + D_DIM + d];
    float ghn = gh[gbase + 2 * D_DIM + d];
    __syncthreads();

    float ir = b_ih[d], iz = b_ih[D_DIM + d], inn = b_ih[2 * D_DIM + d];
    for (int kk = 0; kk < D_DIM; kk++) {
        const float* wi = WT_ih + kk * D3;
        float xk = s_x[k][kk];
        ir += xk * wi[d]; iz += xk * wi[D_DIM + d]; inn += xk * wi[2 * D_DIM + d];
    }
    float r = sigmoidf_(ir + ghr);
    float z = sigmoidf_(iz + ghz);
    float n = tanhf(inn + r * ghn);
    float trans = (1.f - z) * n + z * hd;

    float v = trans * cq[(BSZ + b) * D_DIM + d] * cls_w[d];  // t=1 slice
    for (int off = 32; off > 0; off >>= 1) v += __shfl_xor(v, off, 64);
    if ((tid & 63) == 0) s_part[k][(tid >> 6) & 1] = v;
    __syncthreads();
    if (tid < K_TOP) s_prob[tid] = sigmoidf_(s_part[tid][0] + s_part[tid][1] + cls_b[0]);
    __syncthreads();
    if (d == 0) {
        int idx = b * M_TRI + k * DEG + j;
        obj1[idx] = obj;
        p1[idx] = vj ? sub_p * s_prob[k] : 0.f;
    }

    // split-K ticket: last block per b finalizes
    __syncthreads();
    if (tid == 0) {
        __threadfence();
        s_last = (atomicAdd(&cnt[b], 1) == DEG - 1);
    }
    __syncthreads();
    if (!s_last) return;
    __threadfence();  // acquire: all blocks' records visible

    if (tid < M_TRI) { s_fo[tid] = obj1[b * M_TRI + tid]; s_fp[tid] = p1[b * M_TRI + tid]; }
    __syncthreads();
    if (tid < M_TRI) {
        int o = s_fo[tid];
        float vv = 0.f;
        for (int i = 0; i < M_TRI; i++) if (s_fo[i] == o) vv += s_fp[i];
        out[(size_t)b * E_ENT + o] = vv / fmaxf(vv, 1.f);
    }
}

extern "C" void kernel_launch(void* const* d_in, const int* in_sizes, int n_in,
                              void* d_out, int out_size, void* d_ws, size_t ws_size,
                              hipStream_t stream) {
    const float* start    = (const float*)d_in[0];
    const float* rel_emb  = (const float*)d_in[1];
    const float* step_W   = (const float*)d_in[2];
    const float* step_b   = (const float*)d_in[3];
    const float* W_ih     = (const float*)d_in[4];
    const float* W_hh     = (const float*)d_in[5];
    const float* b_ih     = (const float*)d_in[6];
    const float* b_hh     = (const float*)d_in[7];
    const float* cls_w    = (const float*)d_in[8];
    const float* cls_b    = (const float*)d_in[9];
    const int*   query    = (const int*)d_in[10];
    const int*   kb_triple = (const int*)d_in[11];
    const int*   kb_range  = (const int*)d_in[12];
    float* out = (float*)d_out;

    char* ws = (char*)d_ws;
    float* WT_ih = (float*)ws;  ws += (size_t)D3 * D_DIM * sizeof(float);
    float* WT_hh = (float*)ws;  ws += (size_t)D3 * D_DIM * sizeof(float);
    float* cq    = (float*)ws;  ws += (size_t)2 * BSZ * D_DIM * sizeof(float);
    float* feat  = (float*)ws;  ws += (size_t)BSZ * DEG * D_DIM * sizeof(float);
    int*   objs  = (int*)ws;    ws += (size_t)BSZ * DEG * sizeof(int);
    float* p0    = (float*)ws;  ws += (size_t)BSZ * DEG * sizeof(float);
    ull*   keysA = (ull*)ws;    ws += (size_t)BSZ * NCH * sizeof(ull);
    int*   obj1  = (int*)ws;    ws += (size_t)BSZ * M_TRI * sizeof(int);
    float* p1    = (float*)ws;  ws += (size_t)BSZ * M_TRI * sizeof(float);
    int*   cnt   = (int*)ws;    ws += (size_t)BSZ * sizeof(int);
    int*   pick_i = (int*)ws;   ws += (size_t)BSZ * K_TOP * sizeof(int);
    float* pick_v = (float*)ws; ws += (size_t)BSZ * K_TOP * sizeof(float);
    float* hvec  = (float*)ws;  ws += (size_t)BSZ * K_TOP * D_DIM * sizeof(float);
    float* gh    = (float*)ws;  ws += (size_t)BSZ * K_TOP * D3 * sizeof(float);

    prep_kernel<<<PS_END, 256, 0, stream>>>(
        start, rel_emb, step_W, step_b, query, W_ih, W_hh,
        WT_ih, WT_hh, cq, keysA, cnt, out);

    step0_kernel<<<BSZ * 32, 256, 0, stream>>>(
        keysA, cq, rel_emb, kb_triple, kb_range,
        WT_ih, b_ih, b_hh, cls_w, cls_b,
        feat, objs, p0);

    mid_kernel<<<BSZ, 384, 0, stream>>>(
        objs, p0, feat, WT_hh, b_hh, pick_i, pick_v, hvec, gh);

    step1_kernel<<<BSZ * DEG, 384, 0, stream>>>(
        pick_i, pick_v, hvec, gh, cq, rel_emb, kb_triple, kb_range,
        WT_ih, b_ih, cls_w, cls_b,
        obj1, p1, cnt, out);
}